// Round 14
// baseline (159.596 us; speedup 1.0000x reference)
//
#include <hip/hip_runtime.h>
#include <math.h>

#define BB 16
#define LL 100
#define NCLS 80
#define CPB 282          // candidates enumerated per prep block (256*282 >= 72000)
#define CAP 288          // per-prep-block slice capacity (stride in candg)
#define PREPB 256
#define STRB 768         // stream blocks (class+obj channels, coalesced)
#define GATB 4608        // 16 waves/block * 4608 = 73728 wave-slots (r8 mapping)
#define NTHR 1024

// level constants
__device__ __constant__ int   d_W[3]     = {80, 40, 20};
__device__ __constant__ int   d_HW[3]    = {6400, 1600, 400};
__device__ __constant__ float d_stride[3]= {8.f, 16.f, 32.f};
__device__ __constant__ int   d_gtoff[3] = {0, 307200, 384000};
__device__ __constant__ float d_anch[3][3][2] = {
  {{10.f,13.f},{16.f,30.f},{33.f,23.f}},
  {{30.f,61.f},{62.f,45.f},{59.f,119.f}},
  {{116.f,90.f},{156.f,198.f},{373.f,326.f}}};

// ws layout (4-byte words)
// [0,16)          acc: 0-2 box, 3-5 cls, 6-8 cnt, 9-11 obj, 12-14 corr, 15 pad
// [16,272)        cntg (256)
// [272,74000)     candg, 256 slices of CAP
// [74000,477200)  count: per-cell candidate multiplicity (uint)
#define ACC_OFF   0
#define CNT_OFF   16
#define CANDG_OFF 272
#define COUNT_OFF 74000

__device__ __forceinline__ float softplusf(float t) {
  return fmaxf(t, 0.f) + log1pf(expf(-fabsf(t)));
}
__device__ __forceinline__ float sigmoidf_(float x) {
  return 1.f / (1.f + expf(-x));
}

__device__ __forceinline__ float ciou_(float px, float py, float pw, float ph,
                                       float gx, float gy, float gw, float gh) {
  const float eps = 1e-9f;
  float b1x1 = px - pw*0.5f, b1x2 = px + pw*0.5f;
  float b1y1 = py - ph*0.5f, b1y2 = py + ph*0.5f;
  float b2x1 = gx - gw*0.5f, b2x2 = gx + gw*0.5f;
  float b2y1 = gy - gh*0.5f, b2y2 = gy + gh*0.5f;
  float iw = fmaxf(fminf(b1x2,b2x2) - fmaxf(b1x1,b2x1), 0.f);
  float ih = fmaxf(fminf(b1y2,b2y2) - fmaxf(b1y1,b2y1), 0.f);
  float inter = iw*ih;
  float w1 = b1x2-b1x1, h1 = b1y2-b1y1 + eps;
  float w2 = b2x2-b2x1, h2 = b2y2-b2y1 + eps;
  float uni = w1*h1 + w2*h2 - inter + eps;
  float iou = inter/uni;
  float cw = fmaxf(b1x2,b2x2) - fminf(b1x1,b2x1);
  float ch = fmaxf(b1y2,b2y2) - fminf(b1y1,b2y1);
  float c2 = cw*cw + ch*ch + eps;
  float dx = b2x1+b2x2-b1x1-b1x2;
  float dy = b2y1+b2y2-b1y1-b1y2;
  float rho2 = (dx*dx + dy*dy)*0.25f;
  float at = atanf(w2/h2) - atanf(w1/h1);
  float v = (float)(4.0/(M_PI*M_PI)) * at*at;
  float alpha = v / (1.0f + eps - iou + v);
  return iou - (rho2/c2 + v*alpha);
}

// K0: zero the per-cell count array (1.6 MB; own kernel, rocclr fill is slow)
__global__ __launch_bounds__(256)
void k_zero(uint4* __restrict__ cnt4) {
  int t = blockIdx.x*256 + threadIdx.x;
  if (t < 100800) cnt4[t] = make_uint4(0u,0u,0u,0u);
}

// K1: nlabel + candidate enumeration into slices + per-cell count build;
//     block0 zeroes acc.
__global__ __launch_bounds__(512)
void k_prep(const float* __restrict__ yt, float* __restrict__ acc,
            unsigned int* __restrict__ cntg, unsigned int* __restrict__ candg,
            unsigned int* __restrict__ count)
{
  __shared__ int s_nl[2];
  __shared__ int s_cnt;
  const int blk = blockIdx.x, tid = threadIdx.x;

  if (blk == 0 && tid >= 32 && tid < 48) acc[tid-32] = 0.f;

  if (tid < 2)  s_nl[tid] = 0;
  if (tid == 2) s_cnt = 0;

  const int t0 = blk*CPB;
  const int b_lo = t0/4500;
  int b_hi = (t0 + CPB - 1)/4500; if (b_hi > BB-1) b_hi = BB-1;
  __syncthreads();

  if (tid < LL) {
    const float* row = yt + (size_t)(b_lo*LL + tid)*5;
    if (row[0]+row[1]+row[2]+row[3]+row[4] > 0.f) atomicAdd(&s_nl[0], 1);
  } else if (tid >= 128 && tid < 128+LL && b_hi != b_lo) {
    const float* row = yt + (size_t)(b_hi*LL + (tid-128))*5;
    if (row[0]+row[1]+row[2]+row[3]+row[4] > 0.f) atomicAdd(&s_nl[1], 1);
  }
  __syncthreads();

  if (tid < CPB) {
    int t = t0 + tid;
    if (t < BB*LL*45) {
      int b = t/4500; int rem = t - b*4500;
      int g_loc = rem/45; int rem2 = rem - g_loc*45;
      int lvl = rem2/15, ao = rem2 - lvl*15, a = ao/5, o = ao - a*5;
      const float* row = yt + (size_t)(b*LL + g_loc)*5;
      float s = d_stride[lvl];
      int W = d_W[lvl];
      float cx = (row[0] + row[2]*0.5f)/s;
      float cy = (row[1] + row[3]*0.5f)/s;
      float w = row[2]/s, h = row[3]/s;
      float aw = d_anch[lvl][a][0]/s, ah = d_anch[lvl][a][1]/s;
      float rw = w/aw, rh = h/ah;
      float maxr = fmaxf(fmaxf(rw,1.f/rw), fmaxf(rh,1.f/rh));
      int nl = (b == b_lo) ? s_nl[0] : s_nl[1];
      bool m = (g_loc < nl) && (maxr < 4.0f);
      float fx = cx - floorf(cx), fy = cy - floorf(cy);
      bool c;
      switch (o) {
        case 0: c = true; break;
        case 1: c = (cx > 1.f) && (fx < 0.5f); break;
        case 2: c = (cy > 1.f) && (fy < 0.5f); break;
        case 3: c = (cx < (float)(W-1)) && (fx > 0.5f); break;
        default:c = (cy < (float)(W-1)) && (fy > 0.5f); break;  // H == W
      }
      if (m && c) {
        const float offx[5] = {0.f,-0.5f,0.f,0.5f,0.f};
        const float offy[5] = {0.f,0.f,-0.5f,0.f,0.5f};
        int gx = (int)(cx + offx[o]);
        int gy = (int)(cy + offy[o]);
        int g = b*LL + g_loc;
        unsigned pk = ((unsigned)lvl<<27) | ((unsigned)a<<25) | ((unsigned)g<<14)
                    | ((unsigned)gy<<7) | (unsigned)gx;
        int idx = atomicAdd(&s_cnt, 1);
        candg[blk*CAP + idx] = pk;
        atomicAdd(&count[d_gtoff[lvl] + (b*3 + a)*d_HW[lvl] + gy*W + gx], 1u);
      }
    }
  }
  __syncthreads();
  if (tid == 0) cntg[blk] = (unsigned)s_cnt;
}

// K2: stream blocks (coalesced class+obj channels, softplus predicated on count)
//     + r8 slot-diluted gather blocks (now only 6 lines per candidate).
__global__ __launch_bounds__(NTHR)
void k_main(const float* __restrict__ p0, const float* __restrict__ p1,
            const float* __restrict__ p2, const float* __restrict__ yt,
            const unsigned int* __restrict__ cntg,
            const unsigned int* __restrict__ candg,
            const unsigned int* __restrict__ count,
            float* __restrict__ acc)
{
  __shared__ float s_acc[15];
  const int blk = blockIdx.x, tid = threadIdx.x;
  if (tid < 15) s_acc[tid] = 0.f;
  __syncthreads();

  if (blk < STRB) {
    // ---- stream: tile = (lvl, b, a, chunk, part); thread owns 4 consecutive pos.
    // parts: part0 -> c in [4,25) (obj + 20 cls), part p>0 -> [5+20p, 25+20p)
    int lvl, tile, chunk, part;
    if (blk < 384)      { lvl = 0; tile = blk >> 3; int r = blk & 7; chunk = r >> 2; part = r & 3; }
    else if (blk < 576) { lvl = 1; int r = blk - 384; tile = r >> 2; chunk = 0; part = r & 3; }
    else                { lvl = 2; int r = blk - 576; tile = r >> 2; chunk = 0; part = r & 3; }
    int b = tile / 3, a = tile - 3*(tile/3);
    int HW = d_HW[lvl];
    int pos0 = chunk*4096 + tid*4;
    float so = 0.f, clsp = 0.f;
    if (pos0 < HW) {
      const float* pr = (lvl==0) ? p0 : (lvl==1) ? p1 : p2;
      const float* base = pr + (size_t)(b*255 + a*85)*HW + pos0;
      const uint4 c4 = *(const uint4*)(count + d_gtoff[lvl] + (b*3 + a)*HW + pos0);
      bool any = (c4.x | c4.y | c4.z | c4.w) != 0u;
      int cs = (part == 0) ? 4 : (5 + 20*part);
      int ce = 25 + 20*part;
      float4 S = make_float4(0.f,0.f,0.f,0.f);
      for (int c = cs; c < ce; ++c) {
        const float4 x4 = *(const float4*)(base + (size_t)c*HW);
        if (c == 4) {
          so = softplusf(x4.x) + softplusf(x4.y) + softplusf(x4.z) + softplusf(x4.w);
        } else if (any) {
          if (c4.x) S.x += softplusf(x4.x);
          if (c4.y) S.y += softplusf(x4.y);
          if (c4.z) S.z += softplusf(x4.z);
          if (c4.w) S.w += softplusf(x4.w);
        }
      }
      if (any)
        clsp = (float)c4.x*S.x + (float)c4.y*S.y + (float)c4.z*S.z + (float)c4.w*S.w;
    }
    // wave-reduce (lvl uniform per block), then LDS merge
    for (int off = 1; off < 64; off <<= 1) {
      so   += __shfl_xor(so, off);
      clsp += __shfl_xor(clsp, off);
    }
    if ((tid & 63) == 0) {
      if (so   != 0.f) atomicAdd(&s_acc[9+lvl], so);
      if (clsp != 0.f) atomicAdd(&s_acc[3+lvl], clsp);
    }
  } else {
    // ---- gather: r8 slot-diluted mapping; 6 scattered lines per candidate ----
    int wg = (blk - STRB)*16 + (tid >> 6);   // wave-global in [0, 73728)
    int lane = tid & 63;
    int p = wg / CAP;
    int sIdx = wg - p*CAP;
    if (sIdx < (int)cntg[p]) {
      unsigned pk = candg[p*CAP + sIdx];
      int gx  = pk & 127;
      int gy  = (pk>>7) & 127;
      int g   = (pk>>14) & 2047;
      int a   = (pk>>25) & 3;
      int lvl = (pk>>27) & 3;
      int b = g / LL;
      float s = d_stride[lvl];
      int W = d_W[lvl], HW = d_HW[lvl];
      const float* pr = (lvl==0) ? p0 : (lvl==1) ? p1 : p2;
      const float* row = yt + (size_t)g*5;
      float cx = (row[0] + row[2]*0.5f)/s;
      float cy = (row[1] + row[3]*0.5f)/s;
      float w  = row[2]/s, h = row[3]/s;
      int label = (int)row[4];
      float aw = d_anch[lvl][a][0]/s, ah = d_anch[lvl][a][1]/s;

      const float* base = pr + (size_t)((b*255 + a*85)*HW + gy*W + gx);
      float xv = 0.f;
      if (lane < 6) {
        int ch = (lane < 5) ? lane : (5 + label);
        xv = base[(size_t)ch*HW];
      }
      float x0 = __shfl(xv,0), x1 = __shfl(xv,1), x2 = __shfl(xv,2), x3 = __shfl(xv,3);
      float xobj = __shfl(xv,4);
      float xl   = __shfl(xv,5);

      float pxc = sigmoidf_(x0) + (float)gx;
      float pyc = sigmoidf_(x1) + (float)gy;
      float pw = expf(x2)*aw, ph = expf(x3)*ah;
      float ci = ciou_(pxc,pyc,pw,ph, cx,cy,w,h);

      if (lane == 0) {
        float bx = 1.f - ci;
        float zx = fmaxf(ci, 0.f) * xobj;   // z * x (CIOU_RATIO == 1)
        atomicAdd(&s_acc[lvl],      bx);
        atomicAdd(&s_acc[3+lvl],  -xl);     // cls = (count*S from stream) - x_label
        atomicAdd(&s_acc[6+lvl],   1.f);
        atomicAdd(&s_acc[12+lvl],  zx);
      }
    }
  }
  __syncthreads();
  if (tid < 15 && s_acc[tid] != 0.f) atomicAdd(&acc[tid], s_acc[tid]);
}

// K3: finalize (stream-ordered)
__global__ __launch_bounds__(64)
void k_fin(const float* __restrict__ acc, float* __restrict__ out) {
  if (threadIdx.x != 0) return;
  const float cells[3] = {307200.f, 76800.f, 19200.f};
  float lb = 0.f, lc = 0.f, lo = 0.f;
  for (int l = 0; l < 3; ++l) {
    float nval  = acc[6+l];
    float denom = fmaxf(nval, 1.f);
    if (nval > 0.f) {
      lb += acc[l] / denom;
      lc += acc[3+l] / (denom * (float)NCLS);
    }
    lo += (acc[9+l] - acc[12+l]) / cells[l];
  }
  lb *= 0.05f;
  lc *= 0.58f;   // lo *= 1.0
  out[0] = lb + lo + lc;
  out[1] = lb;
  out[2] = lo;
  out[3] = lc;
}

extern "C" void kernel_launch(void* const* d_in, const int* in_sizes, int n_in,
                              void* d_out, int out_size, void* d_ws, size_t ws_size,
                              hipStream_t stream) {
  const float* p0 = (const float*)d_in[0];
  const float* p1 = (const float*)d_in[1];
  const float* p2 = (const float*)d_in[2];
  const float* yt = (const float*)d_in[3];

  float*        wsf   = (float*)d_ws;
  float*        acc   = wsf + ACC_OFF;
  unsigned int* cntg  = (unsigned int*)(wsf + CNT_OFF);
  unsigned int* candg = (unsigned int*)(wsf + CANDG_OFF);
  unsigned int* count = (unsigned int*)(wsf + COUNT_OFF);

  k_zero<<<394, 256, 0, stream>>>((uint4*)count);
  k_prep<<<PREPB, 512, 0, stream>>>(yt, acc, cntg, candg, count);
  k_main<<<STRB + GATB, NTHR, 0, stream>>>(p0, p1, p2, yt, cntg, candg, count, acc);
  k_fin <<<1, 64, 0, stream>>>(acc, (float*)d_out);
}

// Round 15
// 46.983 us; speedup vs baseline: 3.3969x; 3.3969x over previous
//
#include <hip/hip_runtime.h>
#include <math.h>

#define BB 16
#define LL 100
#define NCLS 80
#define CPB 282          // candidates enumerated per prep block (256*282 >= 72000)
#define CAP 288          // per-prep-block slice capacity (stride in candg)
#define HCAP 144         // half-capacity slot mapping (2 slots per wave)
#define PREPB 256
#define GATB 2304        // 16 waves/block * 2304 = 36864 wave-slots = 256*144
#define OBJB 99          // 99*1024 threads cover 100800 float4 groups
#define NTHR 1024

// level constants
__device__ __constant__ int   d_W[3]     = {80, 40, 20};
__device__ __constant__ int   d_HW[3]    = {6400, 1600, 400};
__device__ __constant__ float d_stride[3]= {8.f, 16.f, 32.f};
__device__ __constant__ int   d_gtoff[3] = {0, 307200, 384000};
__device__ __constant__ float d_anch[3][3][2] = {
  {{10.f,13.f},{16.f,30.f},{33.f,23.f}},
  {{30.f,61.f},{62.f,45.f},{59.f,119.f}},
  {{116.f,90.f},{156.f,198.f},{373.f,326.f}}};

// ws layout (4-byte words)
// [0,16)        acc: 0-2 box, 3-5 cls, 6-8 cnt, 9-11 objA, 12-14 corr, 15 pad
// [16,272)      cntg (256, written unconditionally by k_prep)
// [272,73984)   candg, 256 slices of CAP
#define ACC_OFF   0
#define CNT_OFF   16
#define CANDG_OFF 272

__device__ __forceinline__ float softplusf(float t) {
  return fmaxf(t, 0.f) + log1pf(expf(-fabsf(t)));
}
__device__ __forceinline__ float sigmoidf_(float x) {
  return 1.f / (1.f + expf(-x));
}

__device__ __forceinline__ float ciou_(float px, float py, float pw, float ph,
                                       float gx, float gy, float gw, float gh) {
  const float eps = 1e-9f;
  float b1x1 = px - pw*0.5f, b1x2 = px + pw*0.5f;
  float b1y1 = py - ph*0.5f, b1y2 = py + ph*0.5f;
  float b2x1 = gx - gw*0.5f, b2x2 = gx + gw*0.5f;
  float b2y1 = gy - gh*0.5f, b2y2 = gy + gh*0.5f;
  float iw = fmaxf(fminf(b1x2,b2x2) - fmaxf(b1x1,b2x1), 0.f);
  float ih = fmaxf(fminf(b1y2,b2y2) - fmaxf(b1y1,b2y1), 0.f);
  float inter = iw*ih;
  float w1 = b1x2-b1x1, h1 = b1y2-b1y1 + eps;
  float w2 = b2x2-b2x1, h2 = b2y2-b2y1 + eps;
  float uni = w1*h1 + w2*h2 - inter + eps;
  float iou = inter/uni;
  float cw = fmaxf(b1x2,b2x2) - fminf(b1x1,b2x1);
  float ch = fmaxf(b1y2,b2y2) - fminf(b1y1,b2y1);
  float c2 = cw*cw + ch*ch + eps;
  float dx = b2x1+b2x2-b1x1-b1x2;
  float dy = b2y1+b2y2-b1y1-b1y2;
  float rho2 = (dx*dx + dy*dy)*0.25f;
  float at = atanf(w2/h2) - atanf(w1/h1);
  float v = (float)(4.0/(M_PI*M_PI)) * at*at;
  float alpha = v / (1.0f + eps - iou + v);
  return iou - (rho2/c2 + v*alpha);
}

// K1: nlabel + candidate enumeration into per-block slices; block0 zeroes acc.
__global__ __launch_bounds__(512)
void k_prep(const float* __restrict__ yt, float* __restrict__ acc,
            unsigned int* __restrict__ cntg, unsigned int* __restrict__ candg)
{
  __shared__ int s_nl[2];
  __shared__ int s_cnt;
  const int blk = blockIdx.x, tid = threadIdx.x;

  if (blk == 0 && tid >= 32 && tid < 48) acc[tid-32] = 0.f;

  if (tid < 2)  s_nl[tid] = 0;
  if (tid == 2) s_cnt = 0;

  const int t0 = blk*CPB;
  const int b_lo = t0/4500;
  int b_hi = (t0 + CPB - 1)/4500; if (b_hi > BB-1) b_hi = BB-1;
  __syncthreads();

  if (tid < LL) {
    const float* row = yt + (size_t)(b_lo*LL + tid)*5;
    if (row[0]+row[1]+row[2]+row[3]+row[4] > 0.f) atomicAdd(&s_nl[0], 1);
  } else if (tid >= 128 && tid < 128+LL && b_hi != b_lo) {
    const float* row = yt + (size_t)(b_hi*LL + (tid-128))*5;
    if (row[0]+row[1]+row[2]+row[3]+row[4] > 0.f) atomicAdd(&s_nl[1], 1);
  }
  __syncthreads();

  if (tid < CPB) {
    int t = t0 + tid;
    if (t < BB*LL*45) {
      int b = t/4500; int rem = t - b*4500;
      int g_loc = rem/45; int rem2 = rem - g_loc*45;
      int lvl = rem2/15, ao = rem2 - lvl*15, a = ao/5, o = ao - a*5;
      const float* row = yt + (size_t)(b*LL + g_loc)*5;
      float s = d_stride[lvl];
      int W = d_W[lvl];
      float cx = (row[0] + row[2]*0.5f)/s;
      float cy = (row[1] + row[3]*0.5f)/s;
      float w = row[2]/s, h = row[3]/s;
      float aw = d_anch[lvl][a][0]/s, ah = d_anch[lvl][a][1]/s;
      float rw = w/aw, rh = h/ah;
      float maxr = fmaxf(fmaxf(rw,1.f/rw), fmaxf(rh,1.f/rh));
      int nl = (b == b_lo) ? s_nl[0] : s_nl[1];
      bool m = (g_loc < nl) && (maxr < 4.0f);
      float fx = cx - floorf(cx), fy = cy - floorf(cy);
      bool c;
      switch (o) {
        case 0: c = true; break;
        case 1: c = (cx > 1.f) && (fx < 0.5f); break;
        case 2: c = (cy > 1.f) && (fy < 0.5f); break;
        case 3: c = (cx < (float)(W-1)) && (fx > 0.5f); break;
        default:c = (cy < (float)(W-1)) && (fy > 0.5f); break;  // H == W
      }
      if (m && c) {
        const float offx[5] = {0.f,-0.5f,0.f,0.5f,0.f};
        const float offy[5] = {0.f,0.f,-0.5f,0.f,0.5f};
        int gx = (int)(cx + offx[o]);
        int gy = (int)(cy + offy[o]);
        int g = b*LL + g_loc;
        unsigned pk = ((unsigned)lvl<<27) | ((unsigned)a<<25) | ((unsigned)g<<14)
                    | ((unsigned)gy<<7) | (unsigned)gx;
        int idx = atomicAdd(&s_cnt, 1);
        candg[blk*CAP + idx] = pk;
      }
    }
  }
  __syncthreads();
  if (tid == 0) cntg[blk] = (unsigned)s_cnt;
}

// K2: mid-density slot mapping (2 slots per wave) + objA stream in tail blocks.
__global__ __launch_bounds__(NTHR)
void k_gather(const float* __restrict__ p0, const float* __restrict__ p1,
              const float* __restrict__ p2, const float* __restrict__ yt,
              const unsigned int* __restrict__ cntg,
              const unsigned int* __restrict__ candg,
              float* __restrict__ acc)
{
  __shared__ float s_acc[15];
  const int blk = blockIdx.x, tid = threadIdx.x;
  if (tid < 15) s_acc[tid] = 0.f;
  __syncthreads();

  if (blk < GATB) {
    // ---- wave covers slots s0 and s0+HCAP of slice p (cnt <= 282 < 2*HCAP) ----
    int wg = blk*16 + (tid >> 6);     // wave-global in [0, 36864)
    int lane = tid & 63;
    int p = wg / HCAP;                // prep slice
    int s0 = wg - p*HCAP;             // first slot
    int cnt = (int)cntg[p];
    for (int sIdx = s0; sIdx < cnt; sIdx += HCAP) {
      unsigned pk = candg[p*CAP + sIdx];
      int gx  = pk & 127;
      int gy  = (pk>>7) & 127;
      int g   = (pk>>14) & 2047;
      int a   = (pk>>25) & 3;
      int lvl = (pk>>27) & 3;
      int b = g / LL;
      float s = d_stride[lvl];
      int W = d_W[lvl], HW = d_HW[lvl];
      const float* pr = (lvl==0) ? p0 : (lvl==1) ? p1 : p2;
      const float* row = yt + (size_t)g*5;
      float cx = (row[0] + row[2]*0.5f)/s;
      float cy = (row[1] + row[3]*0.5f)/s;
      float w  = row[2]/s, h = row[3]/s;
      int label = (int)row[4];
      float aw = d_anch[lvl][a][0]/s, ah = d_anch[lvl][a][1]/s;

      const float* base = pr + (size_t)((b*255 + a*85)*HW + gy*W + gx);
      float xA = base[(size_t)lane*HW];
      float xB = (lane < 21) ? base[(size_t)(64+lane)*HW] : 0.f;
      float x0 = __shfl(xA,0), x1 = __shfl(xA,1), x2 = __shfl(xA,2), x3 = __shfl(xA,3);
      float xobj = __shfl(xA,4);      // ch4 logit for obj correction

      float pxc = sigmoidf_(x0) + (float)gx;
      float pyc = sigmoidf_(x1) + (float)gy;
      float pw = expf(x2)*aw, ph = expf(x3)*ah;
      float ci = ciou_(pxc,pyc,pw,ph, cx,cy,w,h);

      float cls = 0.f;
      if (lane >= 5) { int cc = lane-5;  cls += (cc==label) ? softplusf(-xA) : softplusf(xA); }
      if (lane < 21) { int cc = 59+lane; cls += (cc==label) ? softplusf(-xB) : softplusf(xB); }
      for (int off = 1; off < 64; off <<= 1) cls += __shfl_xor(cls, off);

      if (lane == 0) {
        float bx = 1.f - ci;
        float zx = fmaxf(ci, 0.f) * xobj;   // z * x (CIOU_RATIO == 1)
        atomicAdd(&s_acc[lvl],     bx);
        atomicAdd(&s_acc[3+lvl],  cls);
        atomicAdd(&s_acc[6+lvl],  1.f);
        atomicAdd(&s_acc[12+lvl], zx);
      }
    }
  } else {
    // ---- objA: sum softplus(x_ch4) over all cells (coalesced float4) ----
    int gt = (blk - GATB)*NTHR + tid;
    if (gt < 100800) {
      int e0 = gt*4;
      int lvl = (e0 < 307200) ? 0 : (e0 < 384000 ? 1 : 2);
      int HW = d_HW[lvl];
      int idx = e0 - d_gtoff[lvl];
      int b = idx/(3*HW); int r2 = idx - b*3*HW; int a = r2/HW; int pos = r2 - a*HW;
      const float* pr = (lvl==0) ? p0 : (lvl==1) ? p1 : p2;
      const float4 x4 = *(const float4*)(pr + (size_t)((b*255 + a*85 + 4)*HW + pos));
      float sp = softplusf(x4.x) + softplusf(x4.y) + softplusf(x4.z) + softplusf(x4.w);
      atomicAdd(&s_acc[9+lvl], sp);
    }
  }
  __syncthreads();
  if (tid < 15 && s_acc[tid] != 0.f) atomicAdd(&acc[tid], s_acc[tid]);
}

// K3: finalize (stream-ordered; acc writes from k_gather are visible)
__global__ __launch_bounds__(64)
void k_fin(const float* __restrict__ acc, float* __restrict__ out) {
  if (threadIdx.x != 0) return;
  const float cells[3] = {307200.f, 76800.f, 19200.f};
  float lb = 0.f, lc = 0.f, lo = 0.f;
  for (int l = 0; l < 3; ++l) {
    float nval  = acc[6+l];
    float denom = fmaxf(nval, 1.f);
    if (nval > 0.f) {
      lb += acc[l] / denom;
      lc += acc[3+l] / (denom * (float)NCLS);
    }
    lo += (acc[9+l] - acc[12+l]) / cells[l];
  }
  lb *= 0.05f;
  lc *= 0.58f;   // lo *= 1.0
  out[0] = lb + lo + lc;
  out[1] = lb;
  out[2] = lo;
  out[3] = lc;
}

extern "C" void kernel_launch(void* const* d_in, const int* in_sizes, int n_in,
                              void* d_out, int out_size, void* d_ws, size_t ws_size,
                              hipStream_t stream) {
  const float* p0 = (const float*)d_in[0];
  const float* p1 = (const float*)d_in[1];
  const float* p2 = (const float*)d_in[2];
  const float* yt = (const float*)d_in[3];

  float*        wsf   = (float*)d_ws;
  float*        acc   = wsf + ACC_OFF;
  unsigned int* cntg  = (unsigned int*)(wsf + CNT_OFF);
  unsigned int* candg = (unsigned int*)(wsf + CANDG_OFF);

  k_prep  <<<PREPB, 512, 0, stream>>>(yt, acc, cntg, candg);
  k_gather<<<GATB + OBJB, NTHR, 0, stream>>>(p0, p1, p2, yt, cntg, candg, acc);
  k_fin   <<<1, 64, 0, stream>>>(acc, (float*)d_out);
}